// Round 11
// baseline (223.205 us; speedup 1.0000x reference)
//
#include <hip/hip_runtime.h>
#include <math.h>

typedef __attribute__((ext_vector_type(8))) short  short8;
typedef __attribute__((ext_vector_type(4))) float  f32x4;
typedef __attribute__((ext_vector_type(4))) unsigned short u16x4;
typedef __attribute__((ext_vector_type(8))) unsigned short u16x8;
typedef unsigned short u16;

#define B_     2
#define NQ_    1024
#define NK_    8192
#define DIM_   512
#define H_     8
#define DH_    64
#define EPS_   1e-5f
#define SCALE_ 0.125f
#define LOG2E_ 1.4426950408889634f

__device__ __forceinline__ u16 f2bf(float f) {
  unsigned int u = __float_as_uint(f);
  u += 0x7fffu + ((u >> 16) & 1u);
  return (u16)(u >> 16);
}
__device__ __forceinline__ float fmax3(float a, float b, float c) {
  return fmaxf(fmaxf(a, b), c);   // fuses to v_max3_f32
}

// ---------------------------------------------------------------- fused prep
// blocks [0,256): weight transpose+cast | [256,4864): LN->bf16
// [4864,8960): trig tables | [8960,9024): maskf table
__global__ __launch_bounds__(256) void prep_kernel(
    const float* __restrict__ wq, const float* __restrict__ wkv,
    const float* __restrict__ wout,
    const float* __restrict__ xq, const float* __restrict__ xc,
    const float* __restrict__ nw, const float* __restrict__ nb,
    const float* __restrict__ ncw, const float* __restrict__ ncb,
    const float* __restrict__ rq, const float* __restrict__ rc,
    const int* __restrict__ mask,
    u16* __restrict__ wqT, u16* __restrict__ wkvT, u16* __restrict__ woutT,
    u16* __restrict__ xqb, u16* __restrict__ xcb,
    float* __restrict__ cq, float* __restrict__ sq2,
    float* __restrict__ cc, float* __restrict__ sc2,
    float* __restrict__ maskf) {
  __shared__ float tile[64][65];
  const int bid = blockIdx.x;
  const int t = threadIdx.x;
  if (bid < 256) {
    const float* W; u16* WT; int N; int tix;
    if (bid < 64)       { W = wq;   WT = wqT;   N = 512;  tix = bid; }
    else if (bid < 192) { W = wkv;  WT = wkvT;  N = 1024; tix = bid - 64; }
    else                { W = wout; WT = woutT; N = 512;  tix = bid - 192; }
    int ntn = N >> 6;
    int k0 = (tix / ntn) << 6, n0 = (tix % ntn) << 6;
    {
      int kk = t >> 2, nc = (t & 3) << 4;
#pragma unroll
      for (int i = 0; i < 4; ++i) {
        f32x4 v = *(const f32x4*)&W[(size_t)(k0 + kk) * N + n0 + nc + 4 * i];
        tile[kk][nc + 4*i + 0] = v[0];
        tile[kk][nc + 4*i + 1] = v[1];
        tile[kk][nc + 4*i + 2] = v[2];
        tile[kk][nc + 4*i + 3] = v[3];
      }
    }
    __syncthreads();
    {
      int n = t >> 2, kc = (t & 3) << 4;
#pragma unroll
      for (int i = 0; i < 2; ++i) {
        u16x8 o;
#pragma unroll
        for (int j = 0; j < 8; ++j) o[j] = f2bf(tile[kc + 8*i + j][n]);
        *(u16x8*)&WT[(size_t)(n0 + n) * 512 + k0 + kc + 8*i] = o;
      }
    }
  } else if (bid < 4864) {
    int wid = t >> 6, lane = t & 63;
    int row = (bid - 256) * 4 + wid;
    const float* x; const float* w; const float* bb; u16* o; int r;
    if (row < 2048) { x = xq; w = nw;  bb = nb;  o = xqb; r = row; }
    else            { x = xc; w = ncw; bb = ncb; o = xcb; r = row - 2048; }
    const f32x4* px = (const f32x4*)(x + (size_t)r * 512);
    f32x4 v0 = px[lane], v1 = px[lane + 64];
    float s  = v0[0]+v0[1]+v0[2]+v0[3] + v1[0]+v1[1]+v1[2]+v1[3];
    float ss = v0[0]*v0[0]+v0[1]*v0[1]+v0[2]*v0[2]+v0[3]*v0[3]
             + v1[0]*v1[0]+v1[1]*v1[1]+v1[2]*v1[2]+v1[3]*v1[3];
#pragma unroll
    for (int ofs = 32; ofs >= 1; ofs >>= 1) { s += __shfl_xor(s, ofs); ss += __shfl_xor(ss, ofs); }
    float mu = s * (1.f/512.f);
    float var = ss * (1.f/512.f) - mu*mu;
    float rs = rsqrtf(var + EPS_);
    const f32x4* pw = (const f32x4*)w; const f32x4* pb = (const f32x4*)bb;
#pragma unroll
    for (int seg = 0; seg < 2; ++seg) {
      int e4 = lane + 64*seg;
      f32x4 xv = seg ? v1 : v0;
      f32x4 wv = pw[e4], bv = pb[e4];
      u16x4 ov;
#pragma unroll
      for (int c = 0; c < 4; ++c) ov[c] = f2bf((xv[c]-mu)*rs*wv[c] + bv[c]);
      *(u16x4*)&o[(size_t)r*512 + e4*4] = ov;
    }
  } else if (bid < 8960) {
    int i = (bid - 4864) * 256 + t;
    const int NQE = B_*NQ_*DH_;
    const int NCE = B_*NK_*DH_;
    if (i < NQE) { float s, c; sincosf(rq[i], &s, &c); cq[i] = c; sq2[i] = s; }
    if (i < NCE) { float s, c; sincosf(rc[i], &s, &c); cc[i] = c; sc2[i] = s; }
  } else {
    int i = (bid - 8960) * 256 + t;
    maskf[i] = mask[i] ? 1.f : 0.f;
  }
}

// ---------------------------------------------------------------- MFMA GEMM body (reg-prefetch dbuf)
// MODE 0: xqb x wqT  -> rope+, *SCALE*LOG2E -> qb
// MODE 1: xcb x wkvT -> rope+ -> kb [bh][key][64] ; vtg [bh][d][8192] (V rows mask-zeroed)
// MODE 2: aob x woutT + bias -> d_out fp32
template<int MODE>
__device__ __forceinline__ void gemm_body(
    int bid0, u16* __restrict__ smem,
    const u16* __restrict__ Abf, const u16* __restrict__ WT,
    const float* __restrict__ ctab, const float* __restrict__ stab,
    const float* __restrict__ bias, const float* __restrict__ mvf,
    u16* __restrict__ out0, u16* __restrict__ out1, float* __restrict__ outf) {
  constexpr int BM   = (MODE==1) ? 128 : 64;
  constexpr int BN   = (MODE==1) ? 128 : 32;
  constexpr int MR   = BM/64;
  constexpr int NR   = BN/16;
  constexpr int N    = (MODE==1) ? 1024 : 512;
  constexpr int NSEQ = (MODE==1) ? 8192 : 1024;
  constexpr int NBN  = N / BN;
  constexpr int NWG  = (((MODE==1)?16384:2048)/BM) * NBN;
  u16* As = smem;
  u16* Bs = smem + BM*64;
  const int tid = threadIdx.x;
  const int w = tid >> 6, l = tid & 63;
  const int la = l >> 4, lb = l & 15;
  int bid = (bid0 & 7) * (NWG/8) + (bid0 >> 3);
  const int m0 = (bid / NBN) * BM;
  const int n0 = (bid % NBN) * BN;
  f32x4 acc[MR][NR];
#pragma unroll
  for (int i = 0; i < MR; ++i)
#pragma unroll
    for (int j = 0; j < NR; ++j) acc[i][j] = (f32x4){0.f,0.f,0.f,0.f};

  constexpr int APT = BM/32;
  constexpr int BPT = BN/32;
  const int arow = tid / (8/APT);
  const int ag0  = (tid % (8/APT)) * APT;
  const int brow = tid / (8/BPT);
  const int bg0  = (tid % (8/BPT)) * BPT;

  auto loadA = [&](int k0, int g) -> short8 {
    if (MODE == 2) {
      int kk = k0 + g*8;
      int m = m0 + arow;
      return *(const short8*)&Abf[((size_t)((m >> 10)*H_ + (kk >> 6)) * NQ_ + (m & 1023)) * 64 + (kk & 63)];
    } else {
      return *(const short8*)&Abf[(size_t)(m0 + arow) * 512 + k0 + g*8];
    }
  };

  short8 apre[APT], bpre[BPT];
#pragma unroll
  for (int i = 0; i < APT; ++i) apre[i] = loadA(0, ag0 + i);
#pragma unroll
  for (int i = 0; i < BPT; ++i) bpre[i] = *(const short8*)&WT[(size_t)(n0 + brow) * 512 + (bg0 + i)*8];

  for (int k0 = 0; k0 < 512; k0 += 64) {
    if (k0) __syncthreads();
#pragma unroll
    for (int i = 0; i < APT; ++i) {
      int g = ag0 + i;
      *(short8*)&As[arow*64 + ((g ^ (arow & 7)) << 3)] = apre[i];
    }
#pragma unroll
    for (int i = 0; i < BPT; ++i) {
      int g = bg0 + i;
      *(short8*)&Bs[brow*64 + ((g ^ (brow & 7)) << 3)] = bpre[i];
    }
    if (k0 + 64 < 512) {
#pragma unroll
      for (int i = 0; i < APT; ++i) apre[i] = loadA(k0 + 64, ag0 + i);
#pragma unroll
      for (int i = 0; i < BPT; ++i) bpre[i] = *(const short8*)&WT[(size_t)(n0 + brow) * 512 + (k0+64) + (bg0 + i)*8];
    }
    __syncthreads();
#pragma unroll
    for (int h = 0; h < 2; ++h) {
      short8 af[MR], bfr[NR];
#pragma unroll
      for (int i = 0; i < MR; ++i) {
        int row = w*(16*MR) + i*16 + lb;
        int g = (4*h + la) ^ (row & 7);
        af[i] = *(const short8*)&As[row*64 + g*8];
      }
#pragma unroll
      for (int j = 0; j < NR; ++j) {
        int row = j*16 + lb;
        int g = (4*h + la) ^ (row & 7);
        bfr[j] = *(const short8*)&Bs[row*64 + g*8];
      }
#pragma unroll
      for (int i = 0; i < MR; ++i)
#pragma unroll
        for (int j = 0; j < NR; ++j)
          acc[i][j] = __builtin_amdgcn_mfma_f32_16x16x32_bf16(af[i], bfr[j], acc[i][j], 0, 0, 0);
    }
  }

  // ---- epilogue
  if (MODE == 2) {
#pragma unroll
    for (int i = 0; i < MR; ++i)
#pragma unroll
      for (int j = 0; j < NR; ++j) {
        int n = n0 + 16*j + lb;
        float bv = bias[n];
#pragma unroll
        for (int r = 0; r < 4; ++r) {
          int m = m0 + w*(16*MR) + 16*i + 4*la + r;
          outf[(size_t)m * 512 + n] = acc[i][j][r] + bv;
        }
      }
  } else if (MODE == 1 && n0 >= 512) {
#pragma unroll
    for (int i = 0; i < MR; ++i) {
      int mbase = m0 + w*(16*MR) + 16*i + 4*la;
      int bI = mbase >> 13;
      int seq = mbase & 8191;
      f32x4 mkv = *(const f32x4*)&mvf[mbase];
#pragma unroll
      for (int j = 0; j < NR; ++j) {
        int n = n0 + 16*j + lb;
        int e = n - 512, hh = e >> 6, dh = e & 63;
        u16x4 pk4;
#pragma unroll
        for (int r = 0; r < 4; ++r) {
          int m = mbase + r;
          float x = acc[i][j][r];
          float pr = __shfl_xor(x, 1);
          float cv = ctab[(size_t)m*64 + dh];
          float sv = stab[(size_t)m*64 + dh];
          pk4[r] = f2bf((x*cv + ((n & 1) ? pr*sv : -pr*sv)) * mkv[r]);
        }
        *(u16x4*)&out1[((size_t)(bI*H_ + hh)*64 + dh)*8192 + seq] = pk4;
      }
    }
  } else {
#pragma unroll
    for (int i = 0; i < MR; ++i)
#pragma unroll
      for (int j = 0; j < NR; ++j) {
        int n = n0 + 16*j + lb;
        int hh = n >> 6, dh = n & 63;
#pragma unroll
        for (int r = 0; r < 4; ++r) {
          int m = m0 + w*(16*MR) + 16*i + 4*la + r;
          float x = acc[i][j][r];
          float pr = __shfl_xor(x, 1);
          float cv = ctab[(size_t)m*64 + dh];
          float sv = stab[(size_t)m*64 + dh];
          float y = x*cv + ((n & 1) ? pr*sv : -pr*sv);
          if (MODE == 0) y *= SCALE_ * LOG2E_;
          int bI = m / NSEQ, seq = m % NSEQ;
          out0[((size_t)(bI*H_ + hh) * NSEQ + seq) * 64 + dh] = f2bf(y);
        }
      }
  }
}

// merged Q-proj + KV-proj launch: blocks [0,512) MODE0, [512,1536) MODE1
__global__ __launch_bounds__(256) void qkv_kernel(
    const u16* __restrict__ xqb, const u16* __restrict__ wqT,
    const u16* __restrict__ xcb, const u16* __restrict__ wkvT,
    const float* __restrict__ cosq, const float* __restrict__ sinq,
    const float* __restrict__ cosc, const float* __restrict__ sinc,
    const float* __restrict__ maskf,
    u16* __restrict__ qb, u16* __restrict__ kb, u16* __restrict__ vtg) {
  __shared__ u16 smem[16384];
  int b = blockIdx.x;
  if (b < 512) {
    gemm_body<0>(b, smem, xqb, wqT, cosq, sinq, nullptr, nullptr, qb, nullptr, nullptr);
  } else {
    gemm_body<1>(b - 512, smem, xcb, wkvT, cosc, sinc, nullptr, maskf, kb, vtg, nullptr);
  }
}

__global__ __launch_bounds__(256) void gemm2_kernel(
    const u16* __restrict__ aob, const u16* __restrict__ woutT,
    const float* __restrict__ bias, float* __restrict__ out) {
  __shared__ u16 smem[6144];
  gemm_body<2>(blockIdx.x, smem, aob, woutT, nullptr, nullptr, bias, nullptr,
               nullptr, nullptr, out);
}

// ---------------------------------------------------------------- attention
// grid = 16 bh * NS splits * 16 qt (XCD-swizzled). 4 waves x 16 q-rows = QBLK 64.
// KVBLK=128: 2 chunks of 64 keys per staged tile -> half the barriers per key.
// Mask via zeroed V rows + fmaf-masked denominator; max over raw scores.
template<int NS>
__global__ __launch_bounds__(256) void attn_mfma(
    const u16* __restrict__ qb, const u16* __restrict__ kb,
    const u16* __restrict__ vtg, const float* __restrict__ maskf,
    float* __restrict__ Opart, float* __restrict__ mpart, float* __restrict__ lpart) {
  __shared__ u16 Ks[128*64];      // [key][d] swizzled, 16 KB
  __shared__ u16 Vt[64*128];      // [d][key] swizzled, 16 KB
  __shared__ u16 Ps[4*16*64];     // per-wave [q][key] swizzled, 8 KB
  constexpr int NWG = 16*16*NS;
  constexpr int CH  = NWG/8;
  constexpr int LS  = (NS==8) ? 3 : 2;
  int orig = blockIdx.x;
  int wid = (orig & 7) * CH + (orig >> 3);     // bijective (NWG%8==0)
  const int qt = wid & 15;
  const int s  = (wid >> 4) & (NS-1);
  const int bh = wid >> (4 + LS);
  const int bI = bh >> 3;
  const int tid = threadIdx.x;
  const int w = tid >> 6, l = tid & 63;
  const int la = l >> 4, lb = l & 15;
  const int key0 = s * (NK_/NS);

  // Q fragments (B operand; SCALE*LOG2E pre-folded)
  const int qrow = qt*64 + w*16 + lb;
  short8 qf0 = *(const short8*)&qb[(((size_t)bh * NQ_) + qrow) * 64 + 8*la];
  short8 qf1 = *(const short8*)&qb[(((size_t)bh * NQ_) + qrow) * 64 + 32 + 8*la];

  // staging maps (256 threads, 128-key tile)
  const int krow = tid >> 1;          // 0..127
  const int kg0  = (tid & 1) * 4;     // granule base (of 8)
  const int vd   = tid >> 2;          // 0..63
  const int vg0  = (tid & 3) * 4;     // granule base (of 16)
  const u16* kptr = kb  + ((size_t)bh * NK_ + key0 + krow) * 64;
  const u16* vptr = vtg + ((size_t)bh * 64 + vd) * 8192 + key0;
  const int ksw = krow & 7, vsw = vd & 7;
  short8 kpre0 = *(const short8*)&kptr[(kg0+0)*8];
  short8 kpre1 = *(const short8*)&kptr[(kg0+1)*8];
  short8 vpre0 = *(const short8*)&vptr[(vg0+0)*8];
  short8 vpre1 = *(const short8*)&vptr[(vg0+1)*8];
  const float* mrow = maskf + bI*8192 + key0 + 4*la;

  f32x4 accO[4];
#pragma unroll
  for (int j = 0; j < 4; ++j) accO[j] = (f32x4){0.f,0.f,0.f,0.f};
  float m_run = -1e30f, l_run = 0.f;
  constexpr int NT = (NK_/NS)/128;

  const int pbase = (w*16 + lb)*64;
  const int pwofs = (4*la) & 7;

  for (int kt = 0; kt < NT; ++kt) {
    // JIT loads for upper granules of current tile (issued before writes)
    short8 k2 = *(const short8*)&kptr[(size_t)kt*8192 + (kg0+2)*8];
    short8 k3 = *(const short8*)&kptr[(size_t)kt*8192 + (kg0+3)*8];
    short8 v2 = *(const short8*)&vptr[kt*128 + (vg0+2)*8];
    short8 v3 = *(const short8*)&vptr[kt*128 + (vg0+3)*8];
    *(short8*)&Ks[krow*64 + (((kg0+0) ^ ksw) << 3)] = kpre0;
    *(short8*)&Ks[krow*64 + (((kg0+1) ^ ksw) << 3)] = kpre1;
    *(short8*)&Vt[vd*128 + (((vg0+0) ^ vsw) << 3)] = vpre0;
    *(short8*)&Vt[vd*128 + (((vg0+1) ^ vsw) << 3)] = vpre1;
    *(short8*)&Ks[krow*64 + (((kg0+2) ^ ksw) << 3)] = k2;
    *(short8*)&Ks[krow*64 + (((kg0+3) ^ ksw) << 3)] = k3;
    *(short8*)&Vt[vd*128 + (((vg0+2) ^ vsw) << 3)] = v2;
    *(short8*)&Vt[vd*128 + (((vg0+3) ^ vsw) << 3)] = v3;
    if (kt + 1 < NT) {
      kpre0 = *(const short8*)&kptr[(size_t)(kt+1)*8192 + (kg0+0)*8];
      kpre1 = *(const short8*)&kptr[(size_t)(kt+1)*8192 + (kg0+1)*8];
      vpre0 = *(const short8*)&vptr[(kt+1)*128 + (vg0+0)*8];
      vpre1 = *(const short8*)&vptr[(kt+1)*128 + (vg0+1)*8];
    }
    __syncthreads();

#pragma unroll
    for (int c = 0; c < 2; ++c) {
      // S^T = K Q  (output row=key, col=query=lb); scores in exp2 domain
      f32x4 sc[4];
#pragma unroll
      for (int t = 0; t < 4; ++t) sc[t] = (f32x4){0.f,0.f,0.f,0.f};
      __builtin_amdgcn_s_setprio(1);
#pragma unroll
      for (int t = 0; t < 4; ++t) {
        int row = c*64 + t*16 + lb;
        int g0 = la ^ (row & 7);
        int g1 = (4 + la) ^ (row & 7);
        short8 kf0 = *(const short8*)&Ks[row*64 + g0*8];
        short8 kf1 = *(const short8*)&Ks[row*64 + g1*8];
        sc[t] = __builtin_amdgcn_mfma_f32_16x16x32_bf16(kf0, qf0, sc[t], 0, 0, 0);
        sc[t] = __builtin_amdgcn_mfma_f32_16x16x32_bf16(kf1, qf1, sc[t], 0, 0, 0);
      }
      __builtin_amdgcn_s_setprio(0);
      // max over raw scores (over-estimate on masked keys is harmless)
      float a0 = fmax3(sc[0][0], sc[0][1], sc[0][2]);
      float a1 = fmax3(sc[0][3], sc[1][0], sc[1][1]);
      float a2 = fmax3(sc[1][2], sc[1][3], sc[2][0]);
      float a3 = fmax3(sc[2][1], sc[2][2], sc[2][3]);
      float a4 = fmax3(sc[3][0], sc[3][1], sc[3][2]);
      float pmax = fmaxf(fmax3(a0, a1, a2), fmax3(a3, a4, sc[3][3]));
      pmax = fmaxf(pmax, __shfl_xor(pmax, 16));
      pmax = fmaxf(pmax, __shfl_xor(pmax, 32));
      if (!__all(pmax <= m_run + 11.f)) {        // defer-max (exp2 units)
        float mnew = fmaxf(m_run, pmax);
        float scl = __builtin_amdgcn_exp2f(m_run - mnew);
        m_run = mnew;
        l_run *= scl;
        float sr[4];
#pragma unroll
        for (int r = 0; r < 4; ++r) sr[r] = __shfl(scl, (l & 48) | (4*la + r));
#pragma unroll
        for (int j = 0; j < 4; ++j)
#pragma unroll
          for (int r = 0; r < 4; ++r) accO[j][r] *= sr[r];
      }
      // exp + masked denominator + P store
      float l_add = 0.f;
#pragma unroll
      for (int t = 0; t < 4; ++t) {
        f32x4 mk = *(const f32x4*)&mrow[kt*128 + c*64 + t*16];
        float p0 = __builtin_amdgcn_exp2f(sc[t][0] - m_run);
        float p1 = __builtin_amdgcn_exp2f(sc[t][1] - m_run);
        float p2 = __builtin_amdgcn_exp2f(sc[t][2] - m_run);
        float p3 = __builtin_amdgcn_exp2f(sc[t][3] - m_run);
        l_add = fmaf(p0, mk[0], l_add);
        l_add = fmaf(p1, mk[1], l_add);
        l_add = fmaf(p2, mk[2], l_add);
        l_add = fmaf(p3, mk[3], l_add);
        int gst = 2*t + (la >> 1);
        uint2 pp;
        asm("v_cvt_pk_bf16_f32 %0, %1, %2" : "=v"(pp.x) : "v"(p0), "v"(p1));
        asm("v_cvt_pk_bf16_f32 %0, %1, %2" : "=v"(pp.y) : "v"(p2), "v"(p3));
        *(uint2*)&Ps[pbase + ((gst ^ (lb & 7)) << 3) + pwofs] = pp;
      }
      l_run += l_add;
      // O += P V  (masked keys contribute 0: V rows zeroed)
      __builtin_amdgcn_s_setprio(1);
#pragma unroll
      for (int kh = 0; kh < 2; ++kh) {
        int pg = (4*kh + la) ^ (lb & 7);
        short8 pf = *(const short8*)&Ps[pbase + pg*8];
#pragma unroll
        for (int j = 0; j < 4; ++j) {
          int d = j*16 + lb;
          int vg = (c*8 + 4*kh + la) ^ (d & 7);
          short8 vf = *(const short8*)&Vt[d*128 + vg*8];
          accO[j] = __builtin_amdgcn_mfma_f32_16x16x32_bf16(pf, vf, accO[j], 0, 0, 0);
        }
      }
      __builtin_amdgcn_s_setprio(0);
    }
    __syncthreads();
  }

  // deferred cross-lane l reduction (la groups of same query)
  l_run += __shfl_xor(l_run, 16);
  l_run += __shfl_xor(l_run, 32);

  const int qa = qt*64 + w*16;
  const size_t obase = ((size_t)s*16 + bh) * 1024;
#pragma unroll
  for (int j = 0; j < 4; ++j)
#pragma unroll
    for (int r = 0; r < 4; ++r)
      Opart[(obase + qa + 4*la + r) * 64 + j*16 + lb] = accO[j][r];
  if (la == 0) {
    mpart[obase + qa + lb] = m_run;
    lpart[obase + qa + lb] = l_run;
  }
}

// ---------------------------------------------------------------- combine (exp2 units) + rope- -> aob
template<int NS>
__global__ __launch_bounds__(256) void combine_kernel(
    const float* __restrict__ Opart, const float* __restrict__ mpart,
    const float* __restrict__ lpart,
    const float* __restrict__ cosq, const float* __restrict__ sinq,
    u16* __restrict__ aob) {
  const int bid = blockIdx.x;
  const int bh = bid >> 4, qt = bid & 15;
  const int t = threadIdx.x;
  const int ql = t >> 2, ds = (t & 3) << 4;
  const int q = qt*64 + ql;
  const int bI = bh >> 3;
  const size_t rbase = ((size_t)bh << 10) + q;
  float m[NS], li[NS];
  float M = -1e30f;
#pragma unroll
  for (int s = 0; s < NS; ++s) {
    m[s]  = mpart[(size_t)s*16384 + rbase];
    li[s] = lpart[(size_t)s*16384 + rbase];
    M = fmaxf(M, m[s]);
  }
  float ws[NS]; float den = 0.f;
#pragma unroll
  for (int s = 0; s < NS; ++s) { ws[s] = __builtin_amdgcn_exp2f(m[s] - M); den += ws[s]*li[s]; }
  float inv = 1.f / den;
  u16 ob[16];
#pragma unroll
  for (int c = 0; c < 4; ++c) {
    int d0 = ds + 4*c;
    f32x4 o = (f32x4){0.f,0.f,0.f,0.f};
#pragma unroll
    for (int s = 0; s < NS; ++s) {
      f32x4 v = *(const f32x4*)&Opart[((size_t)s*16384 + rbase)*64 + d0];
      o += ws[s] * v;
    }
    o *= inv;
    size_t tix = ((((size_t)bI << 10) + q) << 6) + d0;
    f32x4 cv = *(const f32x4*)&cosq[tix];
    f32x4 sv = *(const f32x4*)&sinq[tix];
    ob[4*c+0] = f2bf(o[0]*cv[0] + o[1]*sv[0]);
    ob[4*c+1] = f2bf(o[1]*cv[1] - o[0]*sv[1]);
    ob[4*c+2] = f2bf(o[2]*cv[2] + o[3]*sv[2]);
    ob[4*c+3] = f2bf(o[3]*cv[3] - o[2]*sv[3]);
  }
  u16x8 w0, w1;
#pragma unroll
  for (int j = 0; j < 8; ++j) { w0[j] = ob[j]; w1[j] = ob[8+j]; }
  *(u16x8*)&aob[rbase*64 + ds]     = w0;
  *(u16x8*)&aob[rbase*64 + ds + 8] = w1;
}

// ---------------------------------------------------------------- launch
extern "C" void kernel_launch(void* const* d_in, const int* in_sizes, int n_in,
                              void* d_out, int out_size, void* d_ws, size_t ws_size,
                              hipStream_t stream) {
  (void)in_sizes; (void)n_in; (void)out_size; (void)ws_size;
  const float* xq   = (const float*)d_in[0];
  const float* xc   = (const float*)d_in[1];
  const float* rq   = (const float*)d_in[2];
  const float* rc   = (const float*)d_in[3];
  const int*   mask = (const int*)d_in[4];
  const float* nw   = (const float*)d_in[5];
  const float* nb   = (const float*)d_in[6];
  const float* ncw  = (const float*)d_in[7];
  const float* ncb  = (const float*)d_in[8];
  const float* wq   = (const float*)d_in[9];
  const float* wkv  = (const float*)d_in[10];
  const float* wout = (const float*)d_in[11];
  const float* bout = (const float*)d_in[12];
  float* out = (float*)d_out;

  // workspace layout (proven R9 structure; NS=4 throughout)
  char* p = (char*)d_ws;
  u16*   woutT  = (u16*)p;   p += 524288;
  float* cosq   = (float*)p; p += 524288;
  float* sinq   = (float*)p; p += 524288;
  u16*   qb     = (u16*)p;   p += 2097152;
  u16*   kb     = (u16*)p;   p += 16777216;
  u16*   vtg    = (u16*)p;   p += 16777216;
  float* mpart4 = (float*)p; p += 262144;
  float* lpart4 = (float*)p; p += 262144;
  u16*   aob    = (u16*)p;   p += 2097152;
  float* maskf  = (float*)aob;                // overlay: maskf dead before combine writes aob
  char* pool = p;
  u16*   wqT   = (u16*)p;   p += 524288;
  u16*   wkvT  = (u16*)p;   p += 1048576;
  u16*   xqb   = (u16*)p;   p += 2097152;
  u16*   xcb   = (u16*)p;   p += 16777216;
  float* cosc  = (float*)p; p += 4194304;
  float* sinc  = (float*)p; p += 4194304;
  float* Opart = (float*)pool;                // overlays pool (dead during attn)

  prep_kernel<<<dim3(9024), dim3(256), 0, stream>>>(
      wq, wkv, wout, xq, xc, nw, nb, ncw, ncb, rq, rc, mask,
      wqT, wkvT, woutT, xqb, xcb, cosq, sinq, cosc, sinc, maskf);
  qkv_kernel<<<dim3(1536), dim3(256), 0, stream>>>(
      xqb, wqT, xcb, wkvT, cosq, sinq, cosc, sinc, maskf, qb, kb, vtg);
  attn_mfma<4><<<dim3(1024), dim3(256), 0, stream>>>(
      qb, kb, vtg, maskf, Opart, mpart4, lpart4);
  combine_kernel<4><<<dim3(256), dim3(256), 0, stream>>>(
      Opart, mpart4, lpart4, cosq, sinq, aob);
  gemm2_kernel<<<dim3(512), dim3(256), 0, stream>>>(aob, woutT, bout, out);
}